// Round 2
// baseline (1481.248 us; speedup 1.0000x reference)
//
#include <hip/hip_runtime.h>

// Problem constants (LocalitySelfAttention): B=8, N=1024, C=1024, H=16, D=64
#define B_ 8
#define N_ 1024
#define C_ 1024
#define H_ 16
#define D_ 64

// ---------------------------------------------------------------------------
// SGEMM: C[M,N] = A[M,K] @ W[K,N] (+ bias), fp32, 128x128 tile, BK=16,
// 256 threads, 8x8 microtile per thread. fp32 has NO MFMA on CDNA4 -> this is
// VALU-bound by design; it is the correctness anchor for a later bf16x3
// (hi/lo split) MFMA version.
// ---------------------------------------------------------------------------
#define BM 128
#define BN 128
#define BK 16

__global__ __launch_bounds__(256) void sgemm_bias(
    const float* __restrict__ A, const float* __restrict__ W,
    const float* __restrict__ bias, float* __restrict__ Cmat,
    int M, int N, int K)
{
    // As stored transposed [k][m], stride 132 floats (528 B -> float4 aligned)
    __shared__ float As[BK][BM + 4];
    __shared__ float Bs[BK][BN];

    const int tid = threadIdx.x;
    const int bm = blockIdx.y * BM;
    const int bn = blockIdx.x * BN;
    const int tx = tid & 15;   // n-direction
    const int ty = tid >> 4;   // m-direction

    const int a_row = tid >> 2;        // 0..63
    const int a_k4  = (tid & 3) * 4;   // 0,4,8,12
    const int b_row = tid >> 5;        // 0..7
    const int b_col = (tid & 31) * 4;  // 0..124

    float acc[8][8];
#pragma unroll
    for (int i = 0; i < 8; ++i)
#pragma unroll
        for (int j = 0; j < 8; ++j) acc[i][j] = 0.f;

    for (int k0 = 0; k0 < K; k0 += BK) {
        // A tile: 128 rows x 16 k, float4 per row-quarter, transposed scatter
#pragma unroll
        for (int r = 0; r < 2; ++r) {
            const int m = a_row + r * 64;
            const float4 v = *(const float4*)&A[(size_t)(bm + m) * K + k0 + a_k4];
            As[a_k4 + 0][m] = v.x;
            As[a_k4 + 1][m] = v.y;
            As[a_k4 + 2][m] = v.z;
            As[a_k4 + 3][m] = v.w;
        }
        // B tile: 16 k-rows x 128 cols, contiguous float4
#pragma unroll
        for (int r = 0; r < 2; ++r) {
            const int kk = b_row + r * 8;
            *(float4*)&Bs[kk][b_col] =
                *(const float4*)&W[(size_t)(k0 + kk) * N + bn + b_col];
        }
        __syncthreads();

#pragma unroll
        for (int kk = 0; kk < BK; ++kk) {
            // wave view: ty in 0..3 within a wave -> As reads are 16-lane
            // broadcasts (free); Bs reads are 2-lane-per-bank (free, m136)
            const float4 a0 = *(const float4*)&As[kk][ty * 4];
            const float4 a1 = *(const float4*)&As[kk][64 + ty * 4];
            const float4 b0 = *(const float4*)&Bs[kk][tx * 4];
            const float4 b1 = *(const float4*)&Bs[kk][64 + tx * 4];
            const float a[8] = {a0.x, a0.y, a0.z, a0.w, a1.x, a1.y, a1.z, a1.w};
            const float b[8] = {b0.x, b0.y, b0.z, b0.w, b1.x, b1.y, b1.z, b1.w};
#pragma unroll
            for (int i = 0; i < 8; ++i)
#pragma unroll
                for (int j = 0; j < 8; ++j)
                    acc[i][j] = fmaf(a[i], b[j], acc[i][j]);
        }
        __syncthreads();
    }

#pragma unroll
    for (int ih = 0; ih < 2; ++ih) {
#pragma unroll
        for (int i = 0; i < 4; ++i) {
            const int row = bm + ih * 64 + ty * 4 + i;
#pragma unroll
            for (int jh = 0; jh < 2; ++jh) {
                const int col = bn + jh * 64 + tx * 4;
                float4 o;
                o.x = acc[ih * 4 + i][jh * 4 + 0];
                o.y = acc[ih * 4 + i][jh * 4 + 1];
                o.z = acc[ih * 4 + i][jh * 4 + 2];
                o.w = acc[ih * 4 + i][jh * 4 + 3];
                if (bias) {
                    o.x += bias[col + 0];
                    o.y += bias[col + 1];
                    o.z += bias[col + 2];
                    o.w += bias[col + 3];
                }
                *(float4*)&Cmat[(size_t)row * N + col] = o;
            }
        }
    }
}

// ---------------------------------------------------------------------------
// Flash-style causal attention (strict mask j < i, matching tril(k=-1)).
// Grid: (N/64, H, B); 256 threads. Per block: 64 query rows, loops key tiles
// of 64. LDS: Qs (Q^T), KS (K^T, reused as P^T after a sync), Vs. ~52 KB.
// Online softmax: per-row state held by 4 threads/row (part = tid&3).
// Fully-masked row 0 -> l==0 -> output 0 (flash convention == reference).
// ---------------------------------------------------------------------------
__global__ __launch_bounds__(256) void attn_causal(
    const float* __restrict__ qkv, const float* __restrict__ scale,
    float* __restrict__ aout)
{
    constexpr int D = D_, BR = 64, BC = 64, LDP = 68; // LDP*4=272B, 16B aligned
    constexpr int C3 = 3 * C_;

    __shared__ float Qs[D][LDP];    // Q^T: Qs[d][r]
    __shared__ float KS[BC][LDP];   // K^T during S-GEMM; P^T after
    __shared__ float Vs[BC][LDP];   // V: Vs[j][d]
    __shared__ float row_alpha[BR];
    __shared__ float row_l[BR];

    const int rt = blockIdx.x;
    const int h  = blockIdx.y;
    const int b  = blockIdx.z;
    const int tid = threadIdx.x;
    const int tx = tid & 15;   // d-direction (PV) / key-direction (S)
    const int ty = tid >> 4;   // row-direction
    const float sc = scale[h];

    // stage Q transposed (coalesced float4 reads)
    for (int c = tid; c < BR * 16; c += 256) {
        const int row = c >> 4;
        const int dq = (c & 15) * 4;
        const float4 v = *(const float4*)
            &qkv[((size_t)(b * N_ + rt * BR + row)) * C3 + h * D + dq];
        Qs[dq + 0][row] = v.x;
        Qs[dq + 1][row] = v.y;
        Qs[dq + 2][row] = v.z;
        Qs[dq + 3][row] = v.w;
    }

    float o[4][4];
#pragma unroll
    for (int i = 0; i < 4; ++i)
#pragma unroll
        for (int j = 0; j < 4; ++j) o[i][j] = 0.f;

    float m_old = -1e30f, l_old = 0.f;
    const int part = tid & 3;
    const int r    = tid >> 2;
    const int ig   = rt * BR + r;   // global query row

    for (int jt = 0; jt <= rt; ++jt) {
        __syncthreads();  // prior KS/Vs reads (and Q staging) complete
        // stage K^T and V for this key tile
        for (int c = tid; c < BC * 16; c += 256) {
            const int row = c >> 4;
            const int dq = (c & 15) * 4;
            const size_t base =
                ((size_t)(b * N_ + jt * BC + row)) * C3 + h * D + dq;
            const float4 kv = *(const float4*)&qkv[base + C_];
            KS[dq + 0][row] = kv.x;
            KS[dq + 1][row] = kv.y;
            KS[dq + 2][row] = kv.z;
            KS[dq + 3][row] = kv.w;
            *(float4*)&Vs[row][dq] = *(const float4*)&qkv[base + 2 * C_];
        }
        __syncthreads();

        // S = Q @ K^T : sacc[i][j] = S[ty*4+i][tx*4+j]
        float sacc[4][4];
#pragma unroll
        for (int i = 0; i < 4; ++i)
#pragma unroll
            for (int j = 0; j < 4; ++j) sacc[i][j] = 0.f;
#pragma unroll
        for (int kk = 0; kk < D; ++kk) {
            const float4 qa = *(const float4*)&Qs[kk][ty * 4];
            const float4 kb = *(const float4*)&KS[kk][tx * 4];
            const float a[4] = {qa.x, qa.y, qa.z, qa.w};
            const float bb[4] = {kb.x, kb.y, kb.z, kb.w};
#pragma unroll
            for (int i = 0; i < 4; ++i)
#pragma unroll
                for (int j = 0; j < 4; ++j)
                    sacc[i][j] = fmaf(a[i], bb[j], sacc[i][j]);
        }
        __syncthreads();  // all K^T reads done; safe to overwrite KS with P^T

        // write scores transposed: KS[j][r]
#pragma unroll
        for (int j = 0; j < 4; ++j) {
            float4 w;
            w.x = sacc[0][j];
            w.y = sacc[1][j];
            w.z = sacc[2][j];
            w.w = sacc[3][j];
            *(float4*)&KS[tx * 4 + j][ty * 4] = w;
        }
        __syncthreads();

        // online softmax: 4 threads per row, each owns 16 keys
        {
            float sv[16];
            float tmax = -1e30f;
#pragma unroll
            for (int jj = 0; jj < 16; ++jj) {
                const int j = part * 16 + jj;
                const int jg = jt * BC + j;
                float s = KS[j][r] * sc;
                s = (jg < ig) ? s : -1e30f;   // strict causal mask
                sv[jj] = s;
                tmax = fmaxf(tmax, s);
            }
            tmax = fmaxf(tmax, __shfl_xor(tmax, 1, 4));
            tmax = fmaxf(tmax, __shfl_xor(tmax, 2, 4));
            const float m_new = fmaxf(m_old, tmax);
            const float alpha = __expf(m_old - m_new); // empty row: exp(0)=1, l stays 0
            float lsum = 0.f;
#pragma unroll
            for (int jj = 0; jj < 16; ++jj) {
                const int j = part * 16 + jj;
                const float p =
                    (sv[jj] > -1e29f) ? __expf(sv[jj] - m_new) : 0.f;
                KS[j][r] = p;
                lsum += p;
            }
            lsum += __shfl_xor(lsum, 1, 4);
            lsum += __shfl_xor(lsum, 2, 4);
            l_old = alpha * l_old + lsum;
            m_old = m_new;
            if (part == 0) { row_alpha[r] = alpha; row_l[r] = l_old; }
        }
        __syncthreads();

        // O = alpha*O + P @ V
        float al[4];
#pragma unroll
        for (int i = 0; i < 4; ++i) al[i] = row_alpha[ty * 4 + i];
#pragma unroll
        for (int i = 0; i < 4; ++i)
#pragma unroll
            for (int j = 0; j < 4; ++j) o[i][j] *= al[i];
#pragma unroll
        for (int kk = 0; kk < BC; ++kk) {
            const float4 pa = *(const float4*)&KS[kk][ty * 4];
            const float4 vb = *(const float4*)&Vs[kk][tx * 4];
            const float p[4] = {pa.x, pa.y, pa.z, pa.w};
            const float v[4] = {vb.x, vb.y, vb.z, vb.w};
#pragma unroll
            for (int i = 0; i < 4; ++i)
#pragma unroll
                for (int j = 0; j < 4; ++j)
                    o[i][j] = fmaf(p[i], v[j], o[i][j]);
        }
    }

    // finalize: divide by l (0 for fully-masked rows), store [B,N,C]
    float linv[4];
#pragma unroll
    for (int i = 0; i < 4; ++i) {
        const float l = row_l[ty * 4 + i];
        linv[i] = (l > 0.f) ? 1.f / l : 0.f;
    }
#pragma unroll
    for (int i = 0; i < 4; ++i) {
        const int n = rt * BR + ty * 4 + i;
        float4 w;
        w.x = o[i][0] * linv[i];
        w.y = o[i][1] * linv[i];
        w.z = o[i][2] * linv[i];
        w.w = o[i][3] * linv[i];
        *(float4*)&aout[((size_t)(b * N_ + n)) * C_ + h * D + tx * 4] = w;
    }
}

// ---------------------------------------------------------------------------
// Launch: x@w_qkv -> qkv(ws) ; attention -> attn_out(ws) ; @w_out+b -> d_out
// Workspace: 96 MB (qkv) + 32 MB (attn_out) = 128 MB of d_ws.
// ---------------------------------------------------------------------------
extern "C" void kernel_launch(void* const* d_in, const int* in_sizes, int n_in,
                              void* d_out, int out_size, void* d_ws, size_t ws_size,
                              hipStream_t stream) {
    (void)in_sizes; (void)n_in; (void)out_size; (void)ws_size;
    const float* x      = (const float*)d_in[0];
    const float* w_qkv  = (const float*)d_in[1];
    const float* scale  = (const float*)d_in[2];
    const float* w_out  = (const float*)d_in[3];
    const float* b_out  = (const float*)d_in[4];
    float* out = (float*)d_out;

    float* qkv      = (float*)d_ws;                        // [B, N, 3C]
    float* attn_out = qkv + (size_t)B_ * N_ * 3 * C_;      // [B, N, C]

    const int M = B_ * N_;

    sgemm_bias<<<dim3(3 * C_ / BN, M / BM), 256, 0, stream>>>(
        x, w_qkv, nullptr, qkv, M, 3 * C_, C_);

    attn_causal<<<dim3(N_ / 64, H_, B_), 256, 0, stream>>>(
        qkv, scale, attn_out);

    sgemm_bias<<<dim3(C_ / BN, M / BM), 256, 0, stream>>>(
        attn_out, w_out, b_out, out, M, C_, C_);
}

// Round 5
// 628.864 us; speedup vs baseline: 2.3554x; 2.3554x over previous
//
#include <hip/hip_runtime.h>

// Problem constants (LocalitySelfAttention): B=8, N=1024, C=1024, H=16, D=64
#define B_ 8
#define N_ 1024
#define C_ 1024
#define H_ 16
#define D_ 64

typedef __attribute__((ext_vector_type(8))) short short8v;      // 8 bf16 (MFMA frag)
typedef __attribute__((ext_vector_type(4))) float f32x4;        // MFMA acc
typedef __attribute__((ext_vector_type(4))) unsigned short ushort4v;

// fp32 -> bf16 (RNE) and back; hi/lo split captures ~16 mantissa bits
__device__ __forceinline__ unsigned short f2bf_rne(float f) {
    unsigned int u = __float_as_uint(f);
    u += 0x7FFFu + ((u >> 16) & 1u);
    return (unsigned short)(u >> 16);
}
__device__ __forceinline__ float bf2f(unsigned short h) {
    return __uint_as_float(((unsigned int)h) << 16);
}

// ---------------------------------------------------------------------------
// Weight pre-pass: W[K][N] f32 -> T_hi/T_lo[N][K] bf16 (convert + transpose).
// 32x32 tiles via padded LDS; ~16 MB total traffic (~10 us).
// ---------------------------------------------------------------------------
__global__ __launch_bounds__(256) void convert_transpose(
    const float* __restrict__ W, unsigned short* __restrict__ T_hi,
    unsigned short* __restrict__ T_lo, int K, int N)
{
    __shared__ float tile[32][33];
    const int nb = blockIdx.x * 32, kb = blockIdx.y * 32;
    const int t = threadIdx.x;
    {
        const int kr = t >> 3, nq = (t & 7) * 4;
        const float4 v = *(const float4*)&W[(size_t)(kb + kr) * N + nb + nq];
        tile[kr][nq + 0] = v.x; tile[kr][nq + 1] = v.y;
        tile[kr][nq + 2] = v.z; tile[kr][nq + 3] = v.w;
    }
    __syncthreads();
    {
        const int nr = t >> 3, kq = (t & 7) * 4;
        ushort4v hv, lv;
#pragma unroll
        for (int j = 0; j < 4; ++j) {
            const float f = tile[kq + j][nr];
            const unsigned short hu = f2bf_rne(f);
            hv[j] = hu;
            lv[j] = f2bf_rne(f - bf2f(hu));
        }
        const size_t o = (size_t)(nb + nr) * K + kb + kq;
        *(ushort4v*)&T_hi[o] = hv;
        *(ushort4v*)&T_lo[o] = lv;
    }
}

// ---------------------------------------------------------------------------
// bf16x3 error-compensated GEMM: C[M,N] = A[M,K] @ Bt[N,K]^T (+bias), fp32-in,
// fp32-out, internally Ahi*Bhi + Ahi*Blo + Alo*Bhi on 16x16x32 bf16 MFMA.
// 128x128 tile, BK=32, 4 waves (2x2), 64x64 per wave = 4x4 fragments.
// LDS XOR-swizzle: byte ^= (row&7)<<4 (bijective triangular map; reads use
// the same mask -> read-what-you-wrote).
// A_F32=1: A is fp32, converted inline during staging (GEMM1: x).
// A_F32=0: A pre-split hi/lo bf16 (GEMM2: attention output).
// ---------------------------------------------------------------------------
template<int A_F32>
__global__ __launch_bounds__(256, 2) void gemm_bf16x3(
    const void* __restrict__ Asrc, const unsigned short* __restrict__ Alo_src,
    const unsigned short* __restrict__ Bt_hi,
    const unsigned short* __restrict__ Bt_lo,
    const float* __restrict__ bias, float* __restrict__ Cmat,
    int M, int N, int K)
{
    __shared__ short As_hi[128 * 32], As_lo[128 * 32];
    __shared__ short Bs_hi[128 * 32], Bs_lo[128 * 32];

    const int tid = threadIdx.x;
    const int lane = tid & 63;
    const int wave = tid >> 6;
    const int wm = wave >> 1, wn = wave & 1;
    const int bm = blockIdx.y * 128, bn = blockIdx.x * 128;
    const int l15 = lane & 15, l4 = lane >> 4;

    f32x4 acc[4][4];
#pragma unroll
    for (int m = 0; m < 4; ++m)
#pragma unroll
        for (int n = 0; n < 4; ++n) acc[m][n] = (f32x4){0.f, 0.f, 0.f, 0.f};

    for (int k0 = 0; k0 < K; k0 += 32) {
        // ---- stage A (hi/lo) ----
        if (A_F32) {
            const float* A = (const float*)Asrc;
#pragma unroll
            for (int c = 0; c < 4; ++c) {
                const int u = tid + 256 * c;        // 128 rows x 8 chunks(4 f32)
                const int row = u >> 3, kc = u & 7;
                const float4 v = *(const float4*)&A[(size_t)(bm + row) * K + k0 + kc * 4];
                const float fv[4] = {v.x, v.y, v.z, v.w};
                ushort4v hv, lv;
#pragma unroll
                for (int j = 0; j < 4; ++j) {
                    const unsigned short hu = f2bf_rne(fv[j]);
                    hv[j] = hu;
                    lv[j] = f2bf_rne(fv[j] - bf2f(hu));
                }
                const int off = (row * 64 + kc * 8) ^ ((row & 7) << 4);
                *(ushort4v*)((char*)As_hi + off) = hv;
                *(ushort4v*)((char*)As_lo + off) = lv;
            }
        } else {
            const unsigned short* Ah = (const unsigned short*)Asrc;
#pragma unroll
            for (int c = 0; c < 2; ++c) {
                const int u = tid + 256 * c;        // 128 rows x 4 granules(8 bf16)
                const int row = u >> 2, kg = u & 3;
                const size_t g = (size_t)(bm + row) * K + k0 + kg * 8;
                const int off = (row * 64 + kg * 16) ^ ((row & 7) << 4);
                *(short8v*)((char*)As_hi + off) = *(const short8v*)&Ah[g];
                *(short8v*)((char*)As_lo + off) = *(const short8v*)&Alo_src[g];
            }
        }
        // ---- stage B (hi/lo), Bt is [N][K] ----
#pragma unroll
        for (int c = 0; c < 2; ++c) {
            const int u = tid + 256 * c;
            const int row = u >> 2, kg = u & 3;
            const size_t g = (size_t)(bn + row) * K + k0 + kg * 8;
            const int off = (row * 64 + kg * 16) ^ ((row & 7) << 4);
            *(short8v*)((char*)Bs_hi + off) = *(const short8v*)&Bt_hi[g];
            *(short8v*)((char*)Bs_lo + off) = *(const short8v*)&Bt_lo[g];
        }
        __syncthreads();

        // ---- fragments: A row=l&15, k=8*(l>>4)+j (one b128 per frag) ----
        short8v ah[4], al[4], bh[4], bl[4];
#pragma unroll
        for (int m = 0; m < 4; ++m) {
            const int row = wm * 64 + m * 16 + l15;
            const int off = (row * 64 + l4 * 16) ^ ((row & 7) << 4);
            ah[m] = *(const short8v*)((char*)As_hi + off);
            al[m] = *(const short8v*)((char*)As_lo + off);
        }
#pragma unroll
        for (int n = 0; n < 4; ++n) {
            const int row = wn * 64 + n * 16 + l15;
            const int off = (row * 64 + l4 * 16) ^ ((row & 7) << 4);
            bh[n] = *(const short8v*)((char*)Bs_hi + off);
            bl[n] = *(const short8v*)((char*)Bs_lo + off);
        }

        // ---- 48 MFMAs: hi*hi + hi*lo + lo*hi into the SAME acc ----
#pragma unroll
        for (int m = 0; m < 4; ++m)
#pragma unroll
            for (int n = 0; n < 4; ++n) {
                acc[m][n] = __builtin_amdgcn_mfma_f32_16x16x32_bf16(
                    ah[m], bh[n], acc[m][n], 0, 0, 0);
                acc[m][n] = __builtin_amdgcn_mfma_f32_16x16x32_bf16(
                    ah[m], bl[n], acc[m][n], 0, 0, 0);
                acc[m][n] = __builtin_amdgcn_mfma_f32_16x16x32_bf16(
                    al[m], bh[n], acc[m][n], 0, 0, 0);
            }
        __syncthreads();
    }

    // ---- epilogue: C/D layout col=lane&15, row=4*(lane>>4)+reg ----
#pragma unroll
    for (int n = 0; n < 4; ++n) {
        const int col = bn + wn * 64 + n * 16 + l15;
        const float bv = bias ? bias[col] : 0.f;
#pragma unroll
        for (int m = 0; m < 4; ++m) {
            const int row0 = bm + wm * 64 + m * 16 + l4 * 4;
#pragma unroll
            for (int r = 0; r < 4; ++r)
                Cmat[(size_t)(row0 + r) * N + col] = acc[m][n][r] + bv;
        }
    }
}

// ---------------------------------------------------------------------------
// Flash-style causal attention (strict mask j < i == tril(k=-1)).
// LPT 1-D grid: rt = 15-(bid>>7) so heavy tiles dispatch first (fixes the
// measured 16x per-CU imbalance: OccupancyPercent was 11.3, VALUBusy 24.8).
// Off-diagonal tiles skip the causal mask. Epilogue emits bf16 hi/lo
// (feeds GEMM2's pre-split A path directly; no f32 attn buffer).
// ---------------------------------------------------------------------------
__global__ __launch_bounds__(256) void attn_causal(
    const float* __restrict__ qkv, const float* __restrict__ scale,
    unsigned short* __restrict__ attn_hi, unsigned short* __restrict__ attn_lo)
{
    constexpr int D = D_, BR = 64, BC = 64, LDP = 68;
    constexpr int C3 = 3 * C_;

    __shared__ float Qs[D][LDP];    // Q^T
    __shared__ float KS[BC][LDP];   // K^T during S-GEMM; P^T after
    __shared__ float Vs[BC][LDP];   // V
    __shared__ float row_alpha[BR];
    __shared__ float row_l[BR];

    const int bid = blockIdx.x;
    const int rt  = 15 - (bid >> 7);
    const int hb  = bid & 127;
    const int h   = hb & 15;
    const int b   = hb >> 4;

    const int tid = threadIdx.x;
    const int tx = tid & 15;
    const int ty = tid >> 4;
    const float sc = scale[h];

    for (int c = tid; c < BR * 16; c += 256) {
        const int row = c >> 4;
        const int dq = (c & 15) * 4;
        const float4 v = *(const float4*)
            &qkv[((size_t)(b * N_ + rt * BR + row)) * C3 + h * D + dq];
        Qs[dq + 0][row] = v.x; Qs[dq + 1][row] = v.y;
        Qs[dq + 2][row] = v.z; Qs[dq + 3][row] = v.w;
    }

    float o[4][4];
#pragma unroll
    for (int i = 0; i < 4; ++i)
#pragma unroll
        for (int j = 0; j < 4; ++j) o[i][j] = 0.f;

    float m_old = -1e30f, l_old = 0.f;
    const int part = tid & 3;
    const int r    = tid >> 2;

    for (int jt = 0; jt <= rt; ++jt) {
        __syncthreads();
        for (int c = tid; c < BC * 16; c += 256) {
            const int row = c >> 4;
            const int dq = (c & 15) * 4;
            const size_t base =
                ((size_t)(b * N_ + jt * BC + row)) * C3 + h * D + dq;
            const float4 kv = *(const float4*)&qkv[base + C_];
            KS[dq + 0][row] = kv.x; KS[dq + 1][row] = kv.y;
            KS[dq + 2][row] = kv.z; KS[dq + 3][row] = kv.w;
            *(float4*)&Vs[row][dq] = *(const float4*)&qkv[base + 2 * C_];
        }
        __syncthreads();

        float sacc[4][4];
#pragma unroll
        for (int i = 0; i < 4; ++i)
#pragma unroll
            for (int j = 0; j < 4; ++j) sacc[i][j] = 0.f;
#pragma unroll
        for (int kk = 0; kk < D; ++kk) {
            const float4 qa = *(const float4*)&Qs[kk][ty * 4];
            const float4 kb = *(const float4*)&KS[kk][tx * 4];
            const float a[4] = {qa.x, qa.y, qa.z, qa.w};
            const float bb[4] = {kb.x, kb.y, kb.z, kb.w};
#pragma unroll
            for (int i = 0; i < 4; ++i)
#pragma unroll
                for (int j = 0; j < 4; ++j)
                    sacc[i][j] = fmaf(a[i], bb[j], sacc[i][j]);
        }
        __syncthreads();

#pragma unroll
        for (int j = 0; j < 4; ++j) {
            float4 w;
            w.x = sacc[0][j]; w.y = sacc[1][j];
            w.z = sacc[2][j]; w.w = sacc[3][j];
            *(float4*)&KS[tx * 4 + j][ty * 4] = w;
        }
        __syncthreads();

        if (jt < rt) {
            float sv[16];
            float tmax = -1e30f;
#pragma unroll
            for (int jj = 0; jj < 16; ++jj) {
                const int j = part * 16 + jj;
                const float s = KS[j][r] * sc;
                sv[jj] = s;
                tmax = fmaxf(tmax, s);
            }
            tmax = fmaxf(tmax, __shfl_xor(tmax, 1, 4));
            tmax = fmaxf(tmax, __shfl_xor(tmax, 2, 4));
            const float m_new = fmaxf(m_old, tmax);
            const float alpha = __expf(m_old - m_new);
            float lsum = 0.f;
#pragma unroll
            for (int jj = 0; jj < 16; ++jj) {
                const int j = part * 16 + jj;
                const float p = __expf(sv[jj] - m_new);
                KS[j][r] = p;
                lsum += p;
            }
            lsum += __shfl_xor(lsum, 1, 4);
            lsum += __shfl_xor(lsum, 2, 4);
            l_old = alpha * l_old + lsum;
            m_old = m_new;
            if (part == 0) { row_alpha[r] = alpha; row_l[r] = l_old; }
        } else {
            float sv[16];
            float tmax = -1e30f;
#pragma unroll
            for (int jj = 0; jj < 16; ++jj) {
                const int j = part * 16 + jj;
                float s = KS[j][r] * sc;
                s = (j < r) ? s : -1e30f;
                sv[jj] = s;
                tmax = fmaxf(tmax, s);
            }
            tmax = fmaxf(tmax, __shfl_xor(tmax, 1, 4));
            tmax = fmaxf(tmax, __shfl_xor(tmax, 2, 4));
            const float m_new = fmaxf(m_old, tmax);
            const float alpha = __expf(m_old - m_new);
            float lsum = 0.f;
#pragma unroll
            for (int jj = 0; jj < 16; ++jj) {
                const int j = part * 16 + jj;
                const float p =
                    (sv[jj] > -1e29f) ? __expf(sv[jj] - m_new) : 0.f;
                KS[j][r] = p;
                lsum += p;
            }
            lsum += __shfl_xor(lsum, 1, 4);
            lsum += __shfl_xor(lsum, 2, 4);
            l_old = alpha * l_old + lsum;
            m_old = m_new;
            if (part == 0) { row_alpha[r] = alpha; row_l[r] = l_old; }
        }
        __syncthreads();

        float al[4];
#pragma unroll
        for (int i = 0; i < 4; ++i) al[i] = row_alpha[ty * 4 + i];
#pragma unroll
        for (int i = 0; i < 4; ++i)
#pragma unroll
            for (int j = 0; j < 4; ++j) o[i][j] *= al[i];
#pragma unroll
        for (int kk = 0; kk < BC; ++kk) {
            const float4 pa = *(const float4*)&KS[kk][ty * 4];
            const float4 vb = *(const float4*)&Vs[kk][tx * 4];
            const float p[4] = {pa.x, pa.y, pa.z, pa.w};
            const float v[4] = {vb.x, vb.y, vb.z, vb.w};
#pragma unroll
            for (int i = 0; i < 4; ++i)
#pragma unroll
                for (int j = 0; j < 4; ++j)
                    o[i][j] = fmaf(p[i], v[j], o[i][j]);
        }
    }

    // finalize: /l, convert to bf16 hi/lo, store [B*N][C] pre-split
    float linv[4];
#pragma unroll
    for (int i = 0; i < 4; ++i) {
        const float l = row_l[ty * 4 + i];
        linv[i] = (l > 0.f) ? 1.f / l : 0.f;
    }
#pragma unroll
    for (int i = 0; i < 4; ++i) {
        const int n = rt * BR + ty * 4 + i;
        ushort4v hv, lv;
#pragma unroll
        for (int j = 0; j < 4; ++j) {
            const float f = o[i][j] * linv[i];
            const unsigned short hu = f2bf_rne(f);
            hv[j] = hu;
            lv[j] = f2bf_rne(f - bf2f(hu));
        }
        const size_t idx = ((size_t)(b * N_ + n)) * C_ + h * D + tx * 4;
        *(ushort4v*)&attn_hi[idx] = hv;
        *(ushort4v*)&attn_lo[idx] = lv;
    }
}

// ---------------------------------------------------------------------------
// ws layout (exactly 128 MB, the round-2-validated bound), with aliasing:
//   [0,96M):    qkv f32 (GEMM1 out, attn in) -- after attn: woutT hi/lo (4M)
//   [96M,128M): wqkvT hi/lo (12M, GEMM1) -- after GEMM1: attn hi/lo (32M)
// Order: convT(w_qkv) -> GEMM1 -> attn -> convT(w_out, into dead qkv) -> GEMM2
// ---------------------------------------------------------------------------
extern "C" void kernel_launch(void* const* d_in, const int* in_sizes, int n_in,
                              void* d_out, int out_size, void* d_ws, size_t ws_size,
                              hipStream_t stream) {
    (void)in_sizes; (void)n_in; (void)out_size; (void)ws_size;
    const float* x      = (const float*)d_in[0];
    const float* w_qkv  = (const float*)d_in[1];
    const float* scale  = (const float*)d_in[2];
    const float* w_out  = (const float*)d_in[3];
    const float* b_out  = (const float*)d_in[4];
    float* out = (float*)d_out;

    char* ws = (char*)d_ws;
    float* qkv = (float*)ws;                                          // 96 MB
    unsigned short* woutT_hi = (unsigned short*)ws;                   // 2 MB
    unsigned short* woutT_lo = (unsigned short*)(ws + ((size_t)2 << 20));
    unsigned short* wqkvT_hi = (unsigned short*)(ws + ((size_t)96 << 20));
    unsigned short* wqkvT_lo = (unsigned short*)(ws + ((size_t)102 << 20));
    unsigned short* attn_hi  = (unsigned short*)(ws + ((size_t)96 << 20));
    unsigned short* attn_lo  = (unsigned short*)(ws + ((size_t)112 << 20));

    const int M = B_ * N_;

    convert_transpose<<<dim3(3 * C_ / 32, C_ / 32), 256, 0, stream>>>(
        w_qkv, wqkvT_hi, wqkvT_lo, C_, 3 * C_);

    gemm_bf16x3<1><<<dim3(3 * C_ / 128, M / 128), 256, 0, stream>>>(
        x, nullptr, wqkvT_hi, wqkvT_lo, nullptr, qkv, M, 3 * C_, C_);

    attn_causal<<<2048, 256, 0, stream>>>(qkv, scale, attn_hi, attn_lo);

    convert_transpose<<<dim3(C_ / 32, C_ / 32), 256, 0, stream>>>(
        w_out, woutT_hi, woutT_lo, C_, C_);

    gemm_bf16x3<0><<<dim3(C_ / 128, M / 128), 256, 0, stream>>>(
        attn_hi, attn_lo, woutT_hi, woutT_lo, b_out, out, M, C_, C_);
}

// Round 6
// 487.530 us; speedup vs baseline: 3.0383x; 1.2899x over previous
//
#include <hip/hip_runtime.h>

// Problem constants (LocalitySelfAttention): B=8, N=1024, C=1024, H=16, D=64
#define B_ 8
#define N_ 1024
#define C_ 1024
#define H_ 16
#define D_ 64

typedef __attribute__((ext_vector_type(8))) short short8v;      // 8 bf16 (MFMA frag)
typedef __attribute__((ext_vector_type(4))) float f32x4;        // MFMA acc
typedef __attribute__((ext_vector_type(4))) unsigned short ushort4v;

// fp32 -> bf16 (RNE) and back; hi/lo split captures ~16 mantissa bits
__device__ __forceinline__ unsigned short f2bf_rne(float f) {
    unsigned int u = __float_as_uint(f);
    u += 0x7FFFu + ((u >> 16) & 1u);
    return (unsigned short)(u >> 16);
}
__device__ __forceinline__ float bf2f(unsigned short h) {
    return __uint_as_float(((unsigned int)h) << 16);
}

// ---------------------------------------------------------------------------
// Weight pre-pass: W[K][N] f32 -> T_hi/T_lo[N][K] bf16 (convert + transpose).
// ---------------------------------------------------------------------------
__global__ __launch_bounds__(256) void convert_transpose(
    const float* __restrict__ W, unsigned short* __restrict__ T_hi,
    unsigned short* __restrict__ T_lo, int K, int N)
{
    __shared__ float tile[32][33];
    const int nb = blockIdx.x * 32, kb = blockIdx.y * 32;
    const int t = threadIdx.x;
    {
        const int kr = t >> 3, nq = (t & 7) * 4;
        const float4 v = *(const float4*)&W[(size_t)(kb + kr) * N + nb + nq];
        tile[kr][nq + 0] = v.x; tile[kr][nq + 1] = v.y;
        tile[kr][nq + 2] = v.z; tile[kr][nq + 3] = v.w;
    }
    __syncthreads();
    {
        const int nr = t >> 3, kq = (t & 7) * 4;
        ushort4v hv, lv;
#pragma unroll
        for (int j = 0; j < 4; ++j) {
            const float f = tile[kq + j][nr];
            const unsigned short hu = f2bf_rne(f);
            hv[j] = hu;
            lv[j] = f2bf_rne(f - bf2f(hu));
        }
        const size_t o = (size_t)(nb + nr) * K + kb + kq;
        *(ushort4v*)&T_hi[o] = hv;
        *(ushort4v*)&T_lo[o] = lv;
    }
}

// ---------------------------------------------------------------------------
// bf16x3 error-compensated GEMM (UNCHANGED, validated round 5).
// ---------------------------------------------------------------------------
template<int A_F32>
__global__ __launch_bounds__(256, 2) void gemm_bf16x3(
    const void* __restrict__ Asrc, const unsigned short* __restrict__ Alo_src,
    const unsigned short* __restrict__ Bt_hi,
    const unsigned short* __restrict__ Bt_lo,
    const float* __restrict__ bias, float* __restrict__ Cmat,
    int M, int N, int K)
{
    __shared__ short As_hi[128 * 32], As_lo[128 * 32];
    __shared__ short Bs_hi[128 * 32], Bs_lo[128 * 32];

    const int tid = threadIdx.x;
    const int lane = tid & 63;
    const int wave = tid >> 6;
    const int wm = wave >> 1, wn = wave & 1;
    const int bm = blockIdx.y * 128, bn = blockIdx.x * 128;
    const int l15 = lane & 15, l4 = lane >> 4;

    f32x4 acc[4][4];
#pragma unroll
    for (int m = 0; m < 4; ++m)
#pragma unroll
        for (int n = 0; n < 4; ++n) acc[m][n] = (f32x4){0.f, 0.f, 0.f, 0.f};

    for (int k0 = 0; k0 < K; k0 += 32) {
        if (A_F32) {
            const float* A = (const float*)Asrc;
#pragma unroll
            for (int c = 0; c < 4; ++c) {
                const int u = tid + 256 * c;
                const int row = u >> 3, kc = u & 7;
                const float4 v = *(const float4*)&A[(size_t)(bm + row) * K + k0 + kc * 4];
                const float fv[4] = {v.x, v.y, v.z, v.w};
                ushort4v hv, lv;
#pragma unroll
                for (int j = 0; j < 4; ++j) {
                    const unsigned short hu = f2bf_rne(fv[j]);
                    hv[j] = hu;
                    lv[j] = f2bf_rne(fv[j] - bf2f(hu));
                }
                const int off = (row * 64 + kc * 8) ^ ((row & 7) << 4);
                *(ushort4v*)((char*)As_hi + off) = hv;
                *(ushort4v*)((char*)As_lo + off) = lv;
            }
        } else {
            const unsigned short* Ah = (const unsigned short*)Asrc;
#pragma unroll
            for (int c = 0; c < 2; ++c) {
                const int u = tid + 256 * c;
                const int row = u >> 2, kg = u & 3;
                const size_t gg = (size_t)(bm + row) * K + k0 + kg * 8;
                const int off = (row * 64 + kg * 16) ^ ((row & 7) << 4);
                *(short8v*)((char*)As_hi + off) = *(const short8v*)&Ah[gg];
                *(short8v*)((char*)As_lo + off) = *(const short8v*)&Alo_src[gg];
            }
        }
#pragma unroll
        for (int c = 0; c < 2; ++c) {
            const int u = tid + 256 * c;
            const int row = u >> 2, kg = u & 3;
            const size_t gg = (size_t)(bn + row) * K + k0 + kg * 8;
            const int off = (row * 64 + kg * 16) ^ ((row & 7) << 4);
            *(short8v*)((char*)Bs_hi + off) = *(const short8v*)&Bt_hi[gg];
            *(short8v*)((char*)Bs_lo + off) = *(const short8v*)&Bt_lo[gg];
        }
        __syncthreads();

        short8v ah[4], al[4], bh[4], bl[4];
#pragma unroll
        for (int m = 0; m < 4; ++m) {
            const int row = wm * 64 + m * 16 + l15;
            const int off = (row * 64 + l4 * 16) ^ ((row & 7) << 4);
            ah[m] = *(const short8v*)((char*)As_hi + off);
            al[m] = *(const short8v*)((char*)As_lo + off);
        }
#pragma unroll
        for (int n = 0; n < 4; ++n) {
            const int row = wn * 64 + n * 16 + l15;
            const int off = (row * 64 + l4 * 16) ^ ((row & 7) << 4);
            bh[n] = *(const short8v*)((char*)Bs_hi + off);
            bl[n] = *(const short8v*)((char*)Bs_lo + off);
        }

#pragma unroll
        for (int m = 0; m < 4; ++m)
#pragma unroll
            for (int n = 0; n < 4; ++n) {
                acc[m][n] = __builtin_amdgcn_mfma_f32_16x16x32_bf16(
                    ah[m], bh[n], acc[m][n], 0, 0, 0);
                acc[m][n] = __builtin_amdgcn_mfma_f32_16x16x32_bf16(
                    ah[m], bl[n], acc[m][n], 0, 0, 0);
                acc[m][n] = __builtin_amdgcn_mfma_f32_16x16x32_bf16(
                    al[m], bh[n], acc[m][n], 0, 0, 0);
            }
        __syncthreads();
    }

#pragma unroll
    for (int n = 0; n < 4; ++n) {
        const int col = bn + wn * 64 + n * 16 + l15;
        const float bv = bias ? bias[col] : 0.f;
#pragma unroll
        for (int m = 0; m < 4; ++m) {
            const int row0 = bm + wm * 64 + m * 16 + l4 * 4;
#pragma unroll
            for (int r = 0; r < 4; ++r)
                Cmat[(size_t)(row0 + r) * N + col] = acc[m][n][r] + bv;
        }
    }
}

// ---------------------------------------------------------------------------
// MFMA flash attention, swapped-operand form. Strict causal mask (j < i).
// Grid: 2048 blocks (LPT: rt = 15-(bid>>7)), 256 thr = 4 waves; wave w owns
// 16 q-rows (q = w*16 + l15). Per key-tile (64 keys):
//   S^T = mfma(A=K, B=Q): lane(l15,g) gets S[key=16kb+4g+r][q=l15]
//     -> softmax per q is IN-LANE (16 vals) + shfl_xor(16,32) across the
//        4 replica lanes. QK^T is bf16x3 (Khi*Qhi+Khi*Qlo+Klo*Qhi).
//   PV  = mfma(A=P, B=V^T): P A-frags gathered from the S^T replicas via
//        16 ds_bpermute/tile (kb = 2t+(g>>1) from lane l15+16*((2g+u)&3));
//        V^T (hi only; error ~2e-3 << budget) staged in LDS by pair-shuffle
//        transpose. All LDS tiles XOR-swizzled byte^=(row&7)<<4 -> b128 frag
//        reads at the 8-cycle wave minimum (uniform bank slots).
// Diagonal tile: wave w computes kb<=w only; mask is (4g+r) < l15 on kb==w.
// Row 0 fully masked -> l=0 -> output 0 (matches reference convention).
// Emits bf16 hi/lo for GEMM2's pre-split A path.
// ---------------------------------------------------------------------------
__global__ __launch_bounds__(256, 2) void attn_mfma(
    const float* __restrict__ qkv, const float* __restrict__ scale,
    unsigned short* __restrict__ attn_hi, unsigned short* __restrict__ attn_lo)
{
    constexpr int C3 = 3 * C_;

    __shared__ short Kh[64 * 64];   // K hi [key][d], byte^=(key&7)<<4
    __shared__ short Kl[64 * 64];   // K lo
    __shared__ short Vt[64 * 64];   // V^T hi [d][key], byte^=(d&7)<<4

    const int bid = blockIdx.x;
    const int rt  = 15 - (bid >> 7);
    const int hb  = bid & 127;
    const int h   = hb & 15;
    const int b   = hb >> 4;

    const int tid  = threadIdx.x;
    const int w    = tid >> 6;
    const int lane = tid & 63;
    const int l15  = lane & 15;
    const int g    = lane >> 4;

    const float sc = scale[h];  // folded into Q (exact: (sc*q)·k = sc*(q·k))

    // ---- Q fragments (B-operand), hi/lo, scale folded ----
    short8v qh[2], ql[2];
    {
        const float* qrow =
            &qkv[((size_t)(b * N_ + rt * 64 + w * 16 + l15)) * C3 + h * D_];
#pragma unroll
        for (int t = 0; t < 2; ++t) {
            const float4 f0 = *(const float4*)&qrow[t * 32 + g * 8];
            const float4 f1 = *(const float4*)&qrow[t * 32 + g * 8 + 4];
            const float fv[8] = {f0.x, f0.y, f0.z, f0.w, f1.x, f1.y, f1.z, f1.w};
            union { short8v v; unsigned short u[8]; } H, L;
#pragma unroll
            for (int j = 0; j < 8; ++j) {
                const float f = fv[j] * sc;
                const unsigned short hu = f2bf_rne(f);
                H.u[j] = hu;
                L.u[j] = f2bf_rne(f - bf2f(hu));
            }
            qh[t] = H.v; ql[t] = L.v;
        }
    }

    f32x4 accO[4];   // O[q=4g+r][d=16n+l15]
#pragma unroll
    for (int n = 0; n < 4; ++n) accO[n] = (f32x4){0.f, 0.f, 0.f, 0.f};
    float m_old = -1e30f, l_old = 0.f;

    for (int jt = 0; jt <= rt; ++jt) {
        __syncthreads();   // prev-tile LDS reads complete

        // ---- stage K (hi+lo) and V^T (hi) for this key tile ----
#pragma unroll
        for (int it = 0; it < 4; ++it) {
            const int u2  = tid + 256 * it;
            const int row = u2 >> 4;          // key 0..63
            const int dq  = (u2 & 15) * 4;    // d quad
            const float* base =
                &qkv[((size_t)(b * N_ + jt * 64 + row)) * C3 + h * D_ + dq];
            const float4 kv = *(const float4*)(base + C_);
            const float kf[4] = {kv.x, kv.y, kv.z, kv.w};
            ushort4v kh4, kl4;
#pragma unroll
            for (int j = 0; j < 4; ++j) {
                const unsigned short hu = f2bf_rne(kf[j]);
                kh4[j] = hu;
                kl4[j] = f2bf_rne(kf[j] - bf2f(hu));
            }
            const int kbyte = (row * 128 + dq * 2) ^ ((row & 7) << 4);
            *(ushort4v*)((char*)Kh + kbyte) = kh4;
            *(ushort4v*)((char*)Kl + kbyte) = kl4;

            // V pair-shuffle transpose: partner tid^16 holds key row^1, same dq.
            const float4 vv = *(const float4*)(base + 2 * C_);
            const float ov[4] = {vv.x, vv.y, vv.z, vv.w};
            float pvv[4];
#pragma unroll
            for (int j = 0; j < 4; ++j) pvv[j] = __shfl_xor(ov[j], 16, 64);
            const int row2 = row & ~1;
            const int odd  = row & 1;
#pragma unroll
            for (int s2 = 0; s2 < 2; ++s2) {
                const int i = odd * 2 + s2;          // even thr: d=dq+0,1; odd: +2,3
                const int d = dq + i;
                const float fe = odd ? pvv[i] : ov[i];   // even key -> low half
                const float fo = odd ? ov[i] : pvv[i];   // odd key  -> high half
                const unsigned int pack =
                    (unsigned int)f2bf_rne(fe) | ((unsigned int)f2bf_rne(fo) << 16);
                const int vbyte = (d * 128 + row2 * 2) ^ ((d & 7) << 4);
                *(unsigned int*)((char*)Vt + vbyte) = pack;
            }
        }
        __syncthreads();

        // ---- S^T = K @ Q^T (bf16x3) ----
        const int kbmax = (jt == rt) ? w : 3;
        f32x4 accS[4];
#pragma unroll
        for (int kb = 0; kb < 4; ++kb) accS[kb] = (f32x4){0.f, 0.f, 0.f, 0.f};
        for (int kb = 0; kb <= kbmax; ++kb) {
#pragma unroll
            for (int t = 0; t < 2; ++t) {
                const int kbyte =
                    ((16 * kb + l15) * 128 + t * 64 + g * 16) ^ ((l15 & 7) << 4);
                const short8v kh = *(const short8v*)((const char*)Kh + kbyte);
                const short8v kl = *(const short8v*)((const char*)Kl + kbyte);
                accS[kb] = __builtin_amdgcn_mfma_f32_16x16x32_bf16(
                    kh, qh[t], accS[kb], 0, 0, 0);
                accS[kb] = __builtin_amdgcn_mfma_f32_16x16x32_bf16(
                    kh, ql[t], accS[kb], 0, 0, 0);
                accS[kb] = __builtin_amdgcn_mfma_f32_16x16x32_bf16(
                    kl, qh[t], accS[kb], 0, 0, 0);
            }
        }

        // ---- online softmax (per q row = l15, replicated over g) ----
        float p[16];
        float tmax = -1e30f;
#pragma unroll
        for (int kb = 0; kb < 4; ++kb) {
#pragma unroll
            for (int r = 0; r < 4; ++r) {
                float s = accS[kb][r];
                bool allow = (kb <= kbmax);
                if (jt == rt && kb == w) allow = allow && ((4 * g + r) < l15);
                s = allow ? s : -1e30f;
                p[kb * 4 + r] = s;
                tmax = fmaxf(tmax, s);
            }
        }
        tmax = fmaxf(tmax, __shfl_xor(tmax, 16, 64));
        tmax = fmaxf(tmax, __shfl_xor(tmax, 32, 64));
        const float m_new = fmaxf(m_old, tmax);
        const float alpha = __expf(m_old - m_new);  // empty row: exp(0)=1, l stays 0
        float lsum = 0.f;
#pragma unroll
        for (int i = 0; i < 16; ++i) {
            const float pe = (p[i] > -1e29f) ? __expf(p[i] - m_new) : 0.f;
            p[i] = pe;
            lsum += pe;
        }
        lsum += __shfl_xor(lsum, 16, 64);
        lsum += __shfl_xor(lsum, 32, 64);
        l_old = alpha * l_old + lsum;
        m_old = m_new;

        // pack P rows to bf16 pairs: pk[kb] = {(r0,r1),(r2,r3)}
        unsigned int pk[4][2];
#pragma unroll
        for (int kb = 0; kb < 4; ++kb) {
            pk[kb][0] = (unsigned int)f2bf_rne(p[kb * 4 + 0]) |
                        ((unsigned int)f2bf_rne(p[kb * 4 + 1]) << 16);
            pk[kb][1] = (unsigned int)f2bf_rne(p[kb * 4 + 2]) |
                        ((unsigned int)f2bf_rne(p[kb * 4 + 3]) << 16);
        }

        // rescale O: lane's O rows are q=4g+r; alpha(q') lives at lane l15'=q'
        float ar[4];
#pragma unroll
        for (int r = 0; r < 4; ++r) ar[r] = __shfl(alpha, 4 * g + r, 64);
#pragma unroll
        for (int n = 0; n < 4; ++n)
#pragma unroll
            for (int r = 0; r < 4; ++r) accO[n][r] *= ar[r];

        // ---- PV: A-frag gather (dest (l15,g), kstep t: quad kb=2t+(g>>1)
        //      u=0 from lane l15+16*((2g)&3), u=1 from l15+16*((2g+1)&3)) ----
        const int s0 = l15 + 16 * ((2 * g) & 3);
        const int s1 = l15 + 16 * ((2 * g + 1) & 3);
        const bool lowg = (g < 2);
#pragma unroll
        for (int t = 0; t < 2; ++t) {
            const int a0 = __shfl((int)pk[2 * t][0], s0, 64);
            const int a1 = __shfl((int)pk[2 * t][1], s0, 64);
            const int b0 = __shfl((int)pk[2 * t + 1][0], s0, 64);
            const int b1 = __shfl((int)pk[2 * t + 1][1], s0, 64);
            const int c0 = __shfl((int)pk[2 * t][0], s1, 64);
            const int c1 = __shfl((int)pk[2 * t][1], s1, 64);
            const int d0 = __shfl((int)pk[2 * t + 1][0], s1, 64);
            const int d1 = __shfl((int)pk[2 * t + 1][1], s1, 64);
            union { short8v v; int u[4]; } A;
            A.u[0] = lowg ? a0 : b0;
            A.u[1] = lowg ? a1 : b1;
            A.u[2] = lowg ? c0 : d0;
            A.u[3] = lowg ? c1 : d1;
#pragma unroll
            for (int n = 0; n < 4; ++n) {
                const int vbyte =
                    ((16 * n + l15) * 128 + t * 64 + g * 16) ^ ((l15 & 7) << 4);
                const short8v vt = *(const short8v*)((const char*)Vt + vbyte);
                accO[n] = __builtin_amdgcn_mfma_f32_16x16x32_bf16(
                    A.v, vt, accO[n], 0, 0, 0);
            }
        }
    }

    // ---- epilogue: /l, emit bf16 hi/lo for GEMM2 ----
    float linv[4];
#pragma unroll
    for (int r = 0; r < 4; ++r) {
        const float lr = __shfl(l_old, 4 * g + r, 64);
        linv[r] = (lr > 0.f) ? 1.f / lr : 0.f;
    }
#pragma unroll
    for (int n = 0; n < 4; ++n) {
#pragma unroll
        for (int r = 0; r < 4; ++r) {
            const float f = accO[n][r] * linv[r];
            const unsigned short hu = f2bf_rne(f);
            const unsigned short lu = f2bf_rne(f - bf2f(hu));
            const size_t idx =
                ((size_t)(b * N_ + rt * 64 + w * 16 + 4 * g + r)) * C_ +
                h * 64 + 16 * n + l15;
            attn_hi[idx] = hu;
            attn_lo[idx] = lu;
        }
    }
}

// ---------------------------------------------------------------------------
// ws layout (128 MB, validated), aliasing unchanged from round 5.
// ---------------------------------------------------------------------------
extern "C" void kernel_launch(void* const* d_in, const int* in_sizes, int n_in,
                              void* d_out, int out_size, void* d_ws, size_t ws_size,
                              hipStream_t stream) {
    (void)in_sizes; (void)n_in; (void)out_size; (void)ws_size;
    const float* x      = (const float*)d_in[0];
    const float* w_qkv  = (const float*)d_in[1];
    const float* scale  = (const float*)d_in[2];
    const float* w_out  = (const float*)d_in[3];
    const float* b_out  = (const float*)d_in[4];
    float* out = (float*)d_out;

    char* ws = (char*)d_ws;
    float* qkv = (float*)ws;                                          // 96 MB
    unsigned short* woutT_hi = (unsigned short*)ws;                   // 2 MB
    unsigned short* woutT_lo = (unsigned short*)(ws + ((size_t)2 << 20));
    unsigned short* wqkvT_hi = (unsigned short*)(ws + ((size_t)96 << 20));
    unsigned short* wqkvT_lo = (unsigned short*)(ws + ((size_t)102 << 20));
    unsigned short* attn_hi  = (unsigned short*)(ws + ((size_t)96 << 20));
    unsigned short* attn_lo  = (unsigned short*)(ws + ((size_t)112 << 20));

    const int M = B_ * N_;

    convert_transpose<<<dim3(3 * C_ / 32, C_ / 32), 256, 0, stream>>>(
        w_qkv, wqkvT_hi, wqkvT_lo, C_, 3 * C_);

    gemm_bf16x3<1><<<dim3(3 * C_ / 128, M / 128), 256, 0, stream>>>(
        x, nullptr, wqkvT_hi, wqkvT_lo, nullptr, qkv, M, 3 * C_, C_);

    attn_mfma<<<2048, 256, 0, stream>>>(qkv, scale, attn_hi, attn_lo);

    convert_transpose<<<dim3(C_ / 32, C_ / 32), 256, 0, stream>>>(
        w_out, woutT_hi, woutT_lo, C_, C_);

    gemm_bf16x3<0><<<dim3(C_ / 128, M / 128), 256, 0, stream>>>(
        attn_hi, attn_lo, woutT_hi, woutT_lo, b_out, out, M, C_, C_);
}

// Round 7
// 413.099 us; speedup vs baseline: 3.5857x; 1.1802x over previous
//
#include <hip/hip_runtime.h>

// Problem constants (LocalitySelfAttention): B=8, N=1024, C=1024, H=16, D=64
#define B_ 8
#define N_ 1024
#define C_ 1024
#define H_ 16
#define D_ 64

typedef __attribute__((ext_vector_type(8))) short short8v;      // 8 bf16 (MFMA frag)
typedef __attribute__((ext_vector_type(4))) float f32x4;        // MFMA acc
typedef __attribute__((ext_vector_type(4))) unsigned short ushort4v;

// fp32 -> bf16 (RNE) and back; hi/lo split captures ~16 mantissa bits
__device__ __forceinline__ unsigned short f2bf_rne(float f) {
    unsigned int u = __float_as_uint(f);
    u += 0x7FFFu + ((u >> 16) & 1u);
    return (unsigned short)(u >> 16);
}
__device__ __forceinline__ float bf2f(unsigned short h) {
    return __uint_as_float(((unsigned int)h) << 16);
}

// async global->LDS DMA, 16B per lane (dest = wave-uniform base + lane*16)
__device__ __forceinline__ void gload16(const void* g, void* l) {
    __builtin_amdgcn_global_load_lds(
        (const __attribute__((address_space(1))) void*)g,
        (__attribute__((address_space(3))) void*)l, 16, 0, 0);
}

// Inverse of the LDS byte swizzle f: p = l ^ ((l>>6 & 7)<<4)  (row stride 64B).
// f flips: bit4^=bit6, bit5^=bit7, bit6^=bit8. Inverse (unit-checked):
__device__ __forceinline__ int inv_swz(int p) {
    int l = p ^ ((p >> 2) & 0x40);   // bit6 ^= bit8
    l ^= ((l >> 6) & 3) << 4;        // bit4 ^= bit6, bit5 ^= bit7
    return l;
}

// ---------------------------------------------------------------------------
// x pre-pass: f32 -> hi/lo bf16, elementwise (A operand of GEMM1; removes the
// 24x-redundant inline conversion measured as VALUBusy=29% in round 6).
// ---------------------------------------------------------------------------
__global__ __launch_bounds__(256) void split_f32(
    const float* __restrict__ in, unsigned short* __restrict__ hi,
    unsigned short* __restrict__ lo, int n4)
{
    for (int i = blockIdx.x * 256 + threadIdx.x; i < n4; i += gridDim.x * 256) {
        const float4 v = *(const float4*)&in[(size_t)i * 4];
        const float f[4] = {v.x, v.y, v.z, v.w};
        ushort4v hv, lv;
#pragma unroll
        for (int j = 0; j < 4; ++j) {
            const unsigned short hu = f2bf_rne(f[j]);
            hv[j] = hu;
            lv[j] = f2bf_rne(f[j] - bf2f(hu));
        }
        *(ushort4v*)&hi[(size_t)i * 4] = hv;
        *(ushort4v*)&lo[(size_t)i * 4] = lv;
    }
}

// ---------------------------------------------------------------------------
// Weight pre-pass: W[K][N] f32 -> T_hi/T_lo[N][K] bf16 (convert + transpose).
// ---------------------------------------------------------------------------
__global__ __launch_bounds__(256) void convert_transpose(
    const float* __restrict__ W, unsigned short* __restrict__ T_hi,
    unsigned short* __restrict__ T_lo, int K, int N)
{
    __shared__ float tile[32][33];
    const int nb = blockIdx.x * 32, kb = blockIdx.y * 32;
    const int t = threadIdx.x;
    {
        const int kr = t >> 3, nq = (t & 7) * 4;
        const float4 v = *(const float4*)&W[(size_t)(kb + kr) * N + nb + nq];
        tile[kr][nq + 0] = v.x; tile[kr][nq + 1] = v.y;
        tile[kr][nq + 2] = v.z; tile[kr][nq + 3] = v.w;
    }
    __syncthreads();
    {
        const int nr = t >> 3, kq = (t & 7) * 4;
        ushort4v hv, lv;
#pragma unroll
        for (int j = 0; j < 4; ++j) {
            const float f = tile[kq + j][nr];
            const unsigned short hu = f2bf_rne(f);
            hv[j] = hu;
            lv[j] = f2bf_rne(f - bf2f(hu));
        }
        const size_t o = (size_t)(nb + nr) * K + kb + kq;
        *(ushort4v*)&T_hi[o] = hv;
        *(ushort4v*)&T_lo[o] = lv;
    }
}

// ---------------------------------------------------------------------------
// bf16x3 GEMM, all operands pre-split hi/lo, staging via global_load_lds w=16.
// LDS linear; the XOR swizzle lives in the per-lane SOURCE address (inv_swz)
// so linear DMA writes produce the swizzled layout the b128 frag reads expect
// (guide rule #21). 128x128 tile, BK=32, 4 waves, 48 MFMA / K-step.
// OUT_SPLIT=1: emit C as bf16 hi/lo (GEMM1 -> qkv pre-split for attn).
// OUT_SPLIT=0: emit f32 + bias (GEMM2 -> d_out).
// ---------------------------------------------------------------------------
template<int OUT_SPLIT>
__global__ __launch_bounds__(256, 2) void gemm_split(
    const unsigned short* __restrict__ A_hi, const unsigned short* __restrict__ A_lo,
    const unsigned short* __restrict__ Bt_hi, const unsigned short* __restrict__ Bt_lo,
    const float* __restrict__ bias, float* __restrict__ Cf,
    unsigned short* __restrict__ C_hi, unsigned short* __restrict__ C_lo,
    int M, int N, int K)
{
    __shared__ short As_hi[128 * 32], As_lo[128 * 32];
    __shared__ short Bs_hi[128 * 32], Bs_lo[128 * 32];

    const int tid = threadIdx.x;
    const int lane = tid & 63;
    const int w = tid >> 6;
    const int wm = w >> 1, wn = w & 1;
    const int bm = blockIdx.y * 128, bn = blockIdx.x * 128;
    const int l15 = lane & 15, l4 = lane >> 4;

    // per-lane staging sources: LDS byte p (linear) <- global element inv_swz(p)
    const unsigned short *pAh[2], *pAl[2], *pBh[2], *pBl[2];
    char *dAh[2], *dAl[2], *dBh[2], *dBl[2];
#pragma unroll
    for (int i = 0; i < 2; ++i) {
        const int p = w * 2048 + i * 1024 + lane * 16;
        const int l = inv_swz(p);
        const int row = l >> 6, kg = (l >> 4) & 3;
        pAh[i] = A_hi + (size_t)(bm + row) * K + kg * 8;
        pAl[i] = A_lo + (size_t)(bm + row) * K + kg * 8;
        pBh[i] = Bt_hi + (size_t)(bn + row) * K + kg * 8;
        pBl[i] = Bt_lo + (size_t)(bn + row) * K + kg * 8;
        dAh[i] = (char*)As_hi + w * 2048 + i * 1024;
        dAl[i] = (char*)As_lo + w * 2048 + i * 1024;
        dBh[i] = (char*)Bs_hi + w * 2048 + i * 1024;
        dBl[i] = (char*)Bs_lo + w * 2048 + i * 1024;
    }

    f32x4 acc[4][4];
#pragma unroll
    for (int m = 0; m < 4; ++m)
#pragma unroll
        for (int n = 0; n < 4; ++n) acc[m][n] = (f32x4){0.f, 0.f, 0.f, 0.f};

    for (int k0 = 0; k0 < K; k0 += 32) {
        // ---- stage: 8 async DMA ops per thread-slot, zero VALU round-trip ----
#pragma unroll
        for (int i = 0; i < 2; ++i) {
            gload16(pAh[i] + k0, dAh[i]);
            gload16(pAl[i] + k0, dAl[i]);
            gload16(pBh[i] + k0, dBh[i]);
            gload16(pBl[i] + k0, dBl[i]);
        }
        __syncthreads();   // compiler drains vmcnt(0) before barrier (m97 structure)

        // ---- fragments (swizzled b128 reads): A row=l&15, k=8*(l>>4)+j ----
        short8v ah[4], al[4], bh[4], bl[4];
#pragma unroll
        for (int m = 0; m < 4; ++m) {
            const int row = wm * 64 + m * 16 + l15;
            const int off = (row * 64 + l4 * 16) ^ ((row & 7) << 4);
            ah[m] = *(const short8v*)((char*)As_hi + off);
            al[m] = *(const short8v*)((char*)As_lo + off);
        }
#pragma unroll
        for (int n = 0; n < 4; ++n) {
            const int row = wn * 64 + n * 16 + l15;
            const int off = (row * 64 + l4 * 16) ^ ((row & 7) << 4);
            bh[n] = *(const short8v*)((char*)Bs_hi + off);
            bl[n] = *(const short8v*)((char*)Bs_lo + off);
        }

        // ---- 48 MFMAs: hi*hi + hi*lo + lo*hi into the SAME acc ----
#pragma unroll
        for (int m = 0; m < 4; ++m)
#pragma unroll
            for (int n = 0; n < 4; ++n) {
                acc[m][n] = __builtin_amdgcn_mfma_f32_16x16x32_bf16(
                    ah[m], bh[n], acc[m][n], 0, 0, 0);
                acc[m][n] = __builtin_amdgcn_mfma_f32_16x16x32_bf16(
                    ah[m], bl[n], acc[m][n], 0, 0, 0);
                acc[m][n] = __builtin_amdgcn_mfma_f32_16x16x32_bf16(
                    al[m], bh[n], acc[m][n], 0, 0, 0);
            }
        __syncthreads();
    }

    // ---- epilogue: C/D layout col=lane&15, row=4*(lane>>4)+reg ----
#pragma unroll
    for (int n = 0; n < 4; ++n) {
        const int col = bn + wn * 64 + n * 16 + l15;
        const float bv = (!OUT_SPLIT && bias) ? bias[col] : 0.f;
#pragma unroll
        for (int m = 0; m < 4; ++m) {
            const int row0 = bm + wm * 64 + m * 16 + l4 * 4;
#pragma unroll
            for (int r = 0; r < 4; ++r) {
                const size_t idx = (size_t)(row0 + r) * N + col;
                if (OUT_SPLIT) {
                    const float f = acc[m][n][r];
                    const unsigned short hu = f2bf_rne(f);
                    C_hi[idx] = hu;
                    C_lo[idx] = f2bf_rne(f - bf2f(hu));
                } else {
                    Cf[idx] = acc[m][n][r] + bv;
                }
            }
        }
    }
}

// ---------------------------------------------------------------------------
// MFMA flash attention, swapped-operand form (validated round 6); now reads
// PRE-SPLIT qkv hi/lo (no f32->bf16 conversion VALU in-loop). scale applied
// to logits (sc*(q.k) == (sc*q).k). Strict causal mask j < i; LPT grid.
// ---------------------------------------------------------------------------
__global__ __launch_bounds__(256, 2) void attn_mfma(
    const unsigned short* __restrict__ qkv_hi,
    const unsigned short* __restrict__ qkv_lo,
    const float* __restrict__ scale,
    unsigned short* __restrict__ attn_hi, unsigned short* __restrict__ attn_lo)
{
    constexpr int C3 = 3 * C_;

    __shared__ short Kh[64 * 64];   // K hi [key][d], byte^=(key&7)<<4
    __shared__ short Kl[64 * 64];   // K lo
    __shared__ short Vt[64 * 64];   // V^T hi [d][key], byte^=(d&7)<<4

    const int bid = blockIdx.x;
    const int rt  = 15 - (bid >> 7);
    const int hb  = bid & 127;
    const int h   = hb & 15;
    const int b   = hb >> 4;

    const int tid  = threadIdx.x;
    const int w    = tid >> 6;
    const int lane = tid & 63;
    const int l15  = lane & 15;
    const int g    = lane >> 4;

    const float sc = scale[h];

    // ---- Q fragments (B-operand): direct b128 loads of pre-split hi/lo ----
    short8v qh[2], ql[2];
    {
        const size_t qoff =
            ((size_t)(b * N_ + rt * 64 + w * 16 + l15)) * C3 + h * D_;
#pragma unroll
        for (int t = 0; t < 2; ++t) {
            qh[t] = *(const short8v*)&qkv_hi[qoff + t * 32 + g * 8];
            ql[t] = *(const short8v*)&qkv_lo[qoff + t * 32 + g * 8];
        }
    }

    f32x4 accO[4];   // O[q=4g+r][d=16n+l15]
#pragma unroll
    for (int n = 0; n < 4; ++n) accO[n] = (f32x4){0.f, 0.f, 0.f, 0.f};
    float m_old = -1e30f, l_old = 0.f;

    for (int jt = 0; jt <= rt; ++jt) {
        __syncthreads();   // prev-tile LDS reads complete

        // ---- stage K (hi+lo): b128 copies, swizzled writes ----
#pragma unroll
        for (int it = 0; it < 2; ++it) {
            const int u2  = tid + 256 * it;
            const int row = u2 >> 3;          // key 0..63
            const int dq8 = u2 & 7;           // 16B granule in d
            const size_t base =
                ((size_t)(b * N_ + jt * 64 + row)) * C3 + C_ + h * D_ + dq8 * 8;
            const int kbyte = (row * 128 + dq8 * 16) ^ ((row & 7) << 4);
            *(short8v*)((char*)Kh + kbyte) = *(const short8v*)&qkv_hi[base];
            *(short8v*)((char*)Kl + kbyte) = *(const short8v*)&qkv_lo[base];
        }
        // ---- stage V^T (hi only): pair-shuffle transpose, packed b32 writes ----
#pragma unroll
        for (int vt = 0; vt < 4; ++vt) {
            const int u2  = tid + 256 * vt;
            const int row = u2 >> 4;          // key
            const int dq  = (u2 & 15) * 4;    // 4 d-values
            const size_t base =
                ((size_t)(b * N_ + jt * 64 + row)) * C3 + 2 * C_ + h * D_ + dq;
            const unsigned long long v8 = *(const unsigned long long*)&qkv_hi[base];
            unsigned short ov[4];
            ov[0] = (unsigned short)v8;
            ov[1] = (unsigned short)(v8 >> 16);
            ov[2] = (unsigned short)(v8 >> 32);
            ov[3] = (unsigned short)(v8 >> 48);
            int pv[4];
#pragma unroll
            for (int j = 0; j < 4; ++j) pv[j] = __shfl_xor((int)ov[j], 16, 64);
            const int row2 = row & ~1;
            const int odd  = row & 1;
#pragma unroll
            for (int s2 = 0; s2 < 2; ++s2) {
                const int i = odd * 2 + s2;
                const int d = dq + i;
                const unsigned int fe = odd ? (unsigned short)pv[i] : ov[i];
                const unsigned int fo = odd ? ov[i] : (unsigned short)pv[i];
                const unsigned int pack = fe | (fo << 16);
                const int vbyte = (d * 128 + row2 * 2) ^ ((d & 7) << 4);
                *(unsigned int*)((char*)Vt + vbyte) = pack;
            }
        }
        __syncthreads();

        // ---- S^T = K @ Q^T (bf16x3) ----
        const int kbmax = (jt == rt) ? w : 3;
        f32x4 accS[4];
#pragma unroll
        for (int kb = 0; kb < 4; ++kb) accS[kb] = (f32x4){0.f, 0.f, 0.f, 0.f};
        for (int kb = 0; kb <= kbmax; ++kb) {
#pragma unroll
            for (int t = 0; t < 2; ++t) {
                const int kbyte =
                    ((16 * kb + l15) * 128 + t * 64 + g * 16) ^ ((l15 & 7) << 4);
                const short8v kh = *(const short8v*)((const char*)Kh + kbyte);
                const short8v kl = *(const short8v*)((const char*)Kl + kbyte);
                accS[kb] = __builtin_amdgcn_mfma_f32_16x16x32_bf16(
                    kh, qh[t], accS[kb], 0, 0, 0);
                accS[kb] = __builtin_amdgcn_mfma_f32_16x16x32_bf16(
                    kh, ql[t], accS[kb], 0, 0, 0);
                accS[kb] = __builtin_amdgcn_mfma_f32_16x16x32_bf16(
                    kl, qh[t], accS[kb], 0, 0, 0);
            }
        }

        // ---- online softmax (per q row = l15, replicated over g) ----
        float p[16];
        float tmax = -1e30f;
#pragma unroll
        for (int kb = 0; kb < 4; ++kb) {
#pragma unroll
            for (int r = 0; r < 4; ++r) {
                float s = accS[kb][r] * sc;    // scale on logits
                bool allow = (kb <= kbmax);
                if (jt == rt && kb == w) allow = allow && ((4 * g + r) < l15);
                s = allow ? s : -1e30f;
                p[kb * 4 + r] = s;
                tmax = fmaxf(tmax, s);
            }
        }
        tmax = fmaxf(tmax, __shfl_xor(tmax, 16, 64));
        tmax = fmaxf(tmax, __shfl_xor(tmax, 32, 64));
        const float m_new = fmaxf(m_old, tmax);
        const float alpha = __expf(m_old - m_new);  // empty row: exp(0)=1, l stays 0
        float lsum = 0.f;
#pragma unroll
        for (int i = 0; i < 16; ++i) {
            const float pe = (p[i] > -1e29f) ? __expf(p[i] - m_new) : 0.f;
            p[i] = pe;
            lsum += pe;
        }
        lsum += __shfl_xor(lsum, 16, 64);
        lsum += __shfl_xor(lsum, 32, 64);
        l_old = alpha * l_old + lsum;
        m_old = m_new;

        // pack P rows to bf16 pairs: pk[kb] = {(r0,r1),(r2,r3)}
        unsigned int pk[4][2];
#pragma unroll
        for (int kb = 0; kb < 4; ++kb) {
            pk[kb][0] = (unsigned int)f2bf_rne(p[kb * 4 + 0]) |
                        ((unsigned int)f2bf_rne(p[kb * 4 + 1]) << 16);
            pk[kb][1] = (unsigned int)f2bf_rne(p[kb * 4 + 2]) |
                        ((unsigned int)f2bf_rne(p[kb * 4 + 3]) << 16);
        }

        // rescale O: lane's O rows are q=4g+r; alpha(q') lives at lane l15'=q'
        float ar[4];
#pragma unroll
        for (int r = 0; r < 4; ++r) ar[r] = __shfl(alpha, 4 * g + r, 64);
#pragma unroll
        for (int n = 0; n < 4; ++n)
#pragma unroll
            for (int r = 0; r < 4; ++r) accO[n][r] *= ar[r];

        // ---- PV: A-frag gather from S^T replicas via lane shuffles ----
        const int s0 = l15 + 16 * ((2 * g) & 3);
        const int s1 = l15 + 16 * ((2 * g + 1) & 3);
        const bool lowg = (g < 2);
#pragma unroll
        for (int t = 0; t < 2; ++t) {
            const int a0 = __shfl((int)pk[2 * t][0], s0, 64);
            const int a1 = __shfl((int)pk[2 * t][1], s0, 64);
            const int b0 = __shfl((int)pk[2 * t + 1][0], s0, 64);
            const int b1 = __shfl((int)pk[2 * t + 1][1], s0, 64);
            const int c0 = __shfl((int)pk[2 * t][0], s1, 64);
            const int c1 = __shfl((int)pk[2 * t][1], s1, 64);
            const int d0 = __shfl((int)pk[2 * t + 1][0], s1, 64);
            const int d1 = __shfl((int)pk[2 * t + 1][1], s1, 64);
            union { short8v v; int u[4]; } A;
            A.u[0] = lowg ? a0 : b0;
            A.u[1] = lowg ? a1 : b1;
            A.u[2] = lowg ? c0 : d0;
            A.u[3] = lowg ? c1 : d1;
#pragma unroll
            for (int n = 0; n < 4; ++n) {
                const int vbyte =
                    ((16 * n + l15) * 128 + t * 64 + g * 16) ^ ((l15 & 7) << 4);
                const short8v vt = *(const short8v*)((const char*)Vt + vbyte);
                accO[n] = __builtin_amdgcn_mfma_f32_16x16x32_bf16(
                    A.v, vt, accO[n], 0, 0, 0);
            }
        }
    }

    // ---- epilogue: /l, emit bf16 hi/lo for GEMM2 ----
    float linv[4];
#pragma unroll
    for (int r = 0; r < 4; ++r) {
        const float lr = __shfl(l_old, 4 * g + r, 64);
        linv[r] = (lr > 0.f) ? 1.f / lr : 0.f;
    }
#pragma unroll
    for (int n = 0; n < 4; ++n) {
#pragma unroll
        for (int r = 0; r < 4; ++r) {
            const float f = accO[n][r] * linv[r];
            const unsigned short hu = f2bf_rne(f);
            const unsigned short lu = f2bf_rne(f - bf2f(hu));
            const size_t idx =
                ((size_t)(b * N_ + rt * 64 + w * 16 + 4 * g + r)) * C_ +
                h * 64 + 16 * n + l15;
            attn_hi[idx] = hu;
            attn_lo[idx] = lu;
        }
    }
}

// ---------------------------------------------------------------------------
// Memory plan (ws <= 128 MB validated bound; d_out doubles as x hi/lo scratch):
//   d_out [0,16M): x_hi   [16,32M): x_lo      (dead after GEMM1; GEMM2 output)
//   ws [0,48M): qkv_hi   [48,96M): qkv_lo     (GEMM1 out, attn in)
//      [96,102M): wqkvT_hi [102,108M): wqkvT_lo  (dead after GEMM1)
//      after attn: attn_hi [96,112M), attn_lo [112,128M)
//      after attn: woutT_hi [0,2M), woutT_lo [2,4M)  (qkv dead)
// Order: split(x) -> convT(w_qkv) -> GEMM1 -> attn -> convT(w_out) -> GEMM2
// ---------------------------------------------------------------------------
extern "C" void kernel_launch(void* const* d_in, const int* in_sizes, int n_in,
                              void* d_out, int out_size, void* d_ws, size_t ws_size,
                              hipStream_t stream) {
    (void)in_sizes; (void)n_in; (void)out_size; (void)ws_size;
    const float* x      = (const float*)d_in[0];
    const float* w_qkv  = (const float*)d_in[1];
    const float* scale  = (const float*)d_in[2];
    const float* w_out  = (const float*)d_in[3];
    const float* b_out  = (const float*)d_in[4];
    float* out = (float*)d_out;

    char* ws = (char*)d_ws;
    unsigned short* x_hi = (unsigned short*)d_out;              // 16 MB
    unsigned short* x_lo = x_hi + (size_t)B_ * N_ * C_;         // 16 MB
    unsigned short* qkv_hi = (unsigned short*)ws;               // 48 MB
    unsigned short* qkv_lo = (unsigned short*)(ws + ((size_t)48 << 20));
    unsigned short* woutT_hi = (unsigned short*)ws;             // 2 MB (after attn)
    unsigned short* woutT_lo = (unsigned short*)(ws + ((size_t)2 << 20));
    unsigned short* wqkvT_hi = (unsigned short*)(ws + ((size_t)96 << 20));
    unsigned short* wqkvT_lo = (unsigned short*)(ws + ((size_t)102 << 20));
    unsigned short* attn_hi  = (unsigned short*)(ws + ((size_t)96 << 20));
    unsigned short* attn_lo  = (unsigned short*)(ws + ((size_t)112 << 20));

    const int M = B_ * N_;

    split_f32<<<2048, 256, 0, stream>>>(x, x_hi, x_lo, M * C_ / 4);

    convert_transpose<<<dim3(3 * C_ / 32, C_ / 32), 256, 0, stream>>>(
        w_qkv, wqkvT_hi, wqkvT_lo, C_, 3 * C_);

    gemm_split<1><<<dim3(3 * C_ / 128, M / 128), 256, 0, stream>>>(
        x_hi, x_lo, wqkvT_hi, wqkvT_lo, nullptr,
        nullptr, qkv_hi, qkv_lo, M, 3 * C_, C_);

    attn_mfma<<<2048, 256, 0, stream>>>(qkv_hi, qkv_lo, scale, attn_hi, attn_lo);

    convert_transpose<<<dim3(C_ / 32, C_ / 32), 256, 0, stream>>>(
        w_out, woutT_hi, woutT_lo, C_, C_);

    gemm_split<0><<<dim3(C_ / 128, M / 128), 256, 0, stream>>>(
        attn_hi, attn_lo, woutT_hi, woutT_lo, b_out,
        out, nullptr, nullptr, M, C_, C_);
}